// Round 3
// baseline (227.439 us; speedup 1.0000x reference)
//
#include <hip/hip_runtime.h>
#include <stdint.h>
#include <math.h>

#define NUM_ANCHORS 5
#define NUM_CLASSES 80
#define MAX_BOXES   50

// Workspace layout (uint32 words):
//   ws[0] : float   sum of p over masked cells
//   ws[1] : uint32  ticket (blocks done)
//   ws[2] : int32   max p as float bits (init 0xFF800000 = -inf)
//   ws[3] : pad
//   ws[4 .. 4+nB)          : uint32 cnt[b]  (unique cells in batch b)
//   ws[4+nB .. +nB*50)     : int32  list, segment b at [b*50, b*50+cnt[b])

__global__ void init_ws(uint32_t* ws, int n_words) {
    int i = threadIdx.x;
    if (i < n_words) ws[i] = (i == 2) ? 0xFF800000u : 0u;
}

// One wave per batch; one lane per GT box. In-wave dedup, per-batch segment.
__global__ void build_list(const float* __restrict__ target,
                           uint32_t* __restrict__ cnt,
                           int* __restrict__ list,
                           int nH, int nW) {
#pragma clang fp contract(off)
    int b = blockIdx.x;
    int lane = threadIdx.x;
    const float* t = target + (long)b * MAX_BOXES * 5;
    float x = 1.0f, y = 0.0f, w = 0.0f, h = 0.0f;
    if (lane < MAX_BOXES) {
        x = t[lane * 5 + 1];
        y = t[lane * 5 + 2];
        w = t[lane * 5 + 3];
        h = t[lane * 5 + 4];
    }
    // valid = cumprod(x != 0): lanes strictly before the first zero box
    unsigned long long zb = __ballot(lane < MAX_BOXES && x == 0.0f);
    int first_zero = zb ? (__ffsll(zb) - 1) : MAX_BOXES;
    bool valid = (lane < MAX_BOXES) && (lane < first_zero);

    int flat = -1 - lane;  // distinct sentinel so invalid lanes never match
    if (valid) {
        float gx = x * (float)nW;
        float gy = y * (float)nH;
        float gw = w * (float)nW;
        float gh = h * (float)nH;
        int gi = min(max((int)floorf(gx), 0), nW - 1);
        int gj = min(max((int)floorf(gy), 0), nH - 1);
        const float aw[NUM_ANCHORS] = {0.57273f, 1.87446f, 3.33843f, 7.88282f, 9.77052f};
        const float ah[NUM_ANCHORS] = {0.677385f, 2.06253f, 5.47434f, 3.52778f, 9.16828f};
        int best = 0; float bestiou = -1.0f;
        #pragma unroll
        for (int n = 0; n < NUM_ANCHORS; ++n) {
            float inter = fminf(gw, aw[n]) * fminf(gh, ah[n]);
            float uni   = gw * gh + aw[n] * ah[n] - inter;
            float iou   = inter / uni;
            if (iou > bestiou) { bestiou = iou; best = n; }  // first-max-wins
        }
        flat = ((b * NUM_ANCHORS + best) * nH + gj) * nW + gi;
    }
    // in-wave dedup: drop lanes whose flat matches an earlier lane
    bool dup = false;
    #pragma unroll
    for (int j = 0; j < MAX_BOXES; ++j) {
        int fj = __shfl(flat, j, 64);
        if (j < lane && fj == flat) dup = true;
    }
    bool keep = valid && !dup;
    unsigned long long kb = __ballot(keep);
    if (keep) {
        int rank = __popcll(kb & ((1ull << lane) - 1ull));
        list[b * MAX_BOXES + rank] = flat;
    }
    if (lane == 0) cnt[b] = (uint32_t)__popcll(kb);
}

// One wave per list slot: 80-class softmax; block-combined atomics;
// last block (ticket) finalizes the two outputs.
__global__ void __launch_bounds__(256)
reduce_fused(const float* __restrict__ output,
             const uint32_t* __restrict__ cnt,
             const int* __restrict__ list,
             float* __restrict__ sumf,
             int* __restrict__ maxbits,
             uint32_t* __restrict__ ticket,
             const int* __restrict__ reqd,
             float* __restrict__ out,
             int HW, int nB) {
    __shared__ float sp[4];
    __shared__ float sm[4];
    int lane = threadIdx.x & 63;
    int wave = threadIdx.x >> 6;
    int g = blockIdx.x * 4 + wave;       // slot in [0, nB*MAX_BOXES)
    int b = g / MAX_BOXES;
    int i = g - b * MAX_BOXES;
    float p = 0.0f, pm = -INFINITY;
    if (b < nB && i < (int)cnt[b]) {
        int cell = list[g];
        int ba = cell / HW;              // b*NUM_ANCHORS + a
        int hw = cell - ba * HW;         // gj*nW + gi
        const float* ptr = output + ((long)(ba * (5 + NUM_CLASSES) + 5)) * HW + hw;
        float v0 = ptr[(long)lane * HW];
        float v1 = (lane < NUM_CLASSES - 64) ? ptr[(long)(lane + 64) * HW] : -INFINITY;
        float mx = fmaxf(v0, v1);
        #pragma unroll
        for (int off = 32; off; off >>= 1) mx = fmaxf(mx, __shfl_xor(mx, off, 64));
        float e0 = expf(v0 - mx);
        float e1 = (lane < NUM_CLASSES - 64) ? expf(v1 - mx) : 0.0f;
        float s = e0 + e1;
        #pragma unroll
        for (int off = 32; off; off >>= 1) s += __shfl_xor(s, off, 64);
        int rq = *reqd;
        float lr = (rq < 64) ? __shfl(v0, rq, 64) : __shfl(v1, rq - 64, 64);
        p = expf(lr - mx) / s;
        pm = p;
    }
    if (lane == 0) { sp[wave] = p; sm[wave] = pm; }
    __syncthreads();
    if (threadIdx.x == 0) {
        float ts = 0.0f, tm = -INFINITY;
        #pragma unroll
        for (int w = 0; w < 4; ++w) { ts += sp[w]; tm = fmaxf(tm, sm[w]); }
        if (tm > -INFINITY) {
            atomicAdd(sumf, ts);
            atomicMax(maxbits, __float_as_int(tm));  // p > 0: int order == float order
        }
        __threadfence();
        uint32_t t = atomicAdd(ticket, 1u);
        if (t == (uint32_t)(gridDim.x - 1)) {
            float s  = atomicAdd(sumf, 0.0f);                 // final value (all adds fenced)
            int   mb = atomicMax(maxbits, (int)0x80000000);   // returns current max
            int total = 0;
            for (int bb = 0; bb < nB; ++bb) total += (int)cnt[bb];
            out[0] = s / (float)total;
            out[1] = __int_as_float(mb);
        }
    }
}

extern "C" void kernel_launch(void* const* d_in, const int* in_sizes, int n_in,
                              void* d_out, int out_size, void* d_ws, size_t ws_size,
                              hipStream_t stream) {
    const float* output = (const float*)d_in[0];
    const float* target = (const float*)d_in[1];
    const int*   reqd   = (const int*)d_in[2];
    float* out = (float*)d_out;

    int nB = in_sizes[1] / (MAX_BOXES * 5);                           // 64
    int HW = in_sizes[0] / (nB * (5 + NUM_CLASSES) * NUM_ANCHORS);    // 1444
    int nW = 1; while (nW * nW < HW) ++nW;                            // 38
    int nH = HW / nW;                                                 // 38

    uint32_t* ws   = (uint32_t*)d_ws;
    float*    sumf = (float*)ws;            // ws[0]
    uint32_t* tick = ws + 1;                // ws[1]
    int*      maxb = (int*)(ws + 2);        // ws[2]
    uint32_t* cnt  = ws + 4;                // ws[4 .. 4+nB)
    int*      list = (int*)(ws + 4 + nB);   // nB*MAX_BOXES slots

    int n_words = 4 + nB;                   // 68
    init_ws<<<1, 128, 0, stream>>>(ws, n_words);

    build_list<<<nB, 64, 0, stream>>>(target, cnt, list, nH, nW);

    int slots = nB * MAX_BOXES;             // 3200
    int rblocks = (slots + 3) / 4;          // 800 blocks, 4 waves each
    reduce_fused<<<rblocks, 256, 0, stream>>>(output, cnt, list, sumf, maxb,
                                              tick, reqd, out, HW, nB);
}

// Round 4
// 225.290 us; speedup vs baseline: 1.0095x; 1.0095x over previous
//
#include <hip/hip_runtime.h>
#include <stdint.h>
#include <math.h>

#define NUM_ANCHORS 5
#define NUM_CLASSES 80
#define MAX_BOXES   50

// Workspace (uint32 words):
//   ws[0] : float   sum of p over masked cells
//   ws[1] : uint32  ticket (blocks done)
//   ws[2] : int32   max p as float bits (init 0xFF800000 = -inf)
//   ws[3] : uint32  total distinct masked cells

__global__ void init_ws(uint32_t* ws) {
    int i = threadIdx.x;
    if (i < 4) ws[i] = (i == 2) ? 0xFF800000u : 0u;
}

// One wave per (batch, box-slot). Each wave recomputes its batch's full
// 50-box mapping in-register (target is L2-resident), derives keep/flat for
// its own slot, and if kept runs the 80-class softmax. i==0 waves contribute
// the batch's distinct-cell count. Last block (ticket) finalizes.
__global__ void __launch_bounds__(256)
fused_all(const float* __restrict__ output,
          const float* __restrict__ target,
          const int* __restrict__ reqd,
          float* __restrict__ sumf,
          int* __restrict__ maxbits,
          uint32_t* __restrict__ ticket,
          uint32_t* __restrict__ total,
          float* __restrict__ out,
          int HW, int nH, int nW, int nB) {
#pragma clang fp contract(off)
    __shared__ float sp[4];
    __shared__ float sm[4];
    int lane = threadIdx.x & 63;
    int wave = threadIdx.x >> 6;
    int g = blockIdx.x * 4 + wave;       // slot in [0, nB*MAX_BOXES)
    int b = g / MAX_BOXES;
    int i = g - b * MAX_BOXES;

    float p = 0.0f, pm = -INFINITY;
    if (b < nB) {
        // lane j holds box j of batch b
        const float* t = target + (long)b * MAX_BOXES * 5;
        float x = 1.0f, y = 0.0f, w = 0.0f, h = 0.0f;
        if (lane < MAX_BOXES) {
            x = t[lane * 5 + 1];
            y = t[lane * 5 + 2];
            w = t[lane * 5 + 3];
            h = t[lane * 5 + 4];
        }
        // valid = cumprod(x != 0): lanes strictly before first zero box
        unsigned long long zb = __ballot(lane < MAX_BOXES && x == 0.0f);
        int first_zero = zb ? (__ffsll(zb) - 1) : MAX_BOXES;
        bool valid = (lane < MAX_BOXES) && (lane < first_zero);

        int flat = -1 - lane;  // distinct sentinel for invalid lanes
        if (valid) {
            float gx = x * (float)nW;
            float gy = y * (float)nH;
            float gw = w * (float)nW;
            float gh = h * (float)nH;
            int gi = min(max((int)floorf(gx), 0), nW - 1);
            int gj = min(max((int)floorf(gy), 0), nH - 1);
            const float aw[NUM_ANCHORS] = {0.57273f, 1.87446f, 3.33843f, 7.88282f, 9.77052f};
            const float ah[NUM_ANCHORS] = {0.677385f, 2.06253f, 5.47434f, 3.52778f, 9.16828f};
            int best = 0; float bestiou = -1.0f;
            #pragma unroll
            for (int n = 0; n < NUM_ANCHORS; ++n) {
                float inter = fminf(gw, aw[n]) * fminf(gh, ah[n]);
                float uni   = gw * gh + aw[n] * ah[n] - inter;
                float iou   = inter / uni;
                if (iou > bestiou) { bestiou = iou; best = n; }  // first-max-wins
            }
            flat = ((b * NUM_ANCHORS + best) * nH + gj) * nW + gi;
        }
        // in-wave dedup: lane kept iff no earlier lane maps to same cell
        bool dup = false;
        #pragma unroll
        for (int j = 0; j < MAX_BOXES; ++j) {
            int fj = __shfl(flat, j, 64);
            if (j < lane && fj == flat) dup = true;
        }
        unsigned long long kb = __ballot(valid && !dup);

        // one wave per batch contributes the distinct count
        if (i == 0 && lane == 0) atomicAdd(total, (uint32_t)__popcll(kb));

        // this wave's own slot
        if ((kb >> i) & 1ull) {
            int cell = __shfl(flat, i, 64);
            int ba = cell / HW;              // b*NUM_ANCHORS + a
            int hw = cell - ba * HW;         // gj*nW + gi
            const float* ptr = output + ((long)(ba * (5 + NUM_CLASSES) + 5)) * HW + hw;
            float v0 = ptr[(long)lane * HW];
            float v1 = (lane < NUM_CLASSES - 64) ? ptr[(long)(lane + 64) * HW] : -INFINITY;
            float mx = fmaxf(v0, v1);
            #pragma unroll
            for (int off = 32; off; off >>= 1) mx = fmaxf(mx, __shfl_xor(mx, off, 64));
            float e0 = expf(v0 - mx);
            float e1 = (lane < NUM_CLASSES - 64) ? expf(v1 - mx) : 0.0f;
            float s = e0 + e1;
            #pragma unroll
            for (int off = 32; off; off >>= 1) s += __shfl_xor(s, off, 64);
            int rq = *reqd;
            float lr = (rq < 64) ? __shfl(v0, rq, 64) : __shfl(v1, rq - 64, 64);
            p = expf(lr - mx) / s;
            pm = p;
        }
    }
    if (lane == 0) { sp[wave] = p; sm[wave] = pm; }
    __syncthreads();   // also drains each wave's outstanding memory ops (incl. count atomic)
    if (threadIdx.x == 0) {
        float ts = 0.0f, tm = -INFINITY;
        #pragma unroll
        for (int w = 0; w < 4; ++w) { ts += sp[w]; tm = fmaxf(tm, sm[w]); }
        if (tm > -INFINITY) {
            atomicAdd(sumf, ts);
            atomicMax(maxbits, __float_as_int(tm));  // p > 0: int order == float order
        }
        __threadfence();
        uint32_t t = atomicAdd(ticket, 1u);
        if (t == (uint32_t)(gridDim.x - 1)) {
            // read final values via RMW no-ops (coherent, bypasses stale L1)
            float    s  = atomicAdd(sumf, 0.0f);
            int      mb = atomicMax(maxbits, (int)0x80000000);
            uint32_t tc = atomicAdd(total, 0u);
            out[0] = s / (float)tc;
            out[1] = __int_as_float(mb);
        }
    }
}

extern "C" void kernel_launch(void* const* d_in, const int* in_sizes, int n_in,
                              void* d_out, int out_size, void* d_ws, size_t ws_size,
                              hipStream_t stream) {
    const float* output = (const float*)d_in[0];
    const float* target = (const float*)d_in[1];
    const int*   reqd   = (const int*)d_in[2];
    float* out = (float*)d_out;

    int nB = in_sizes[1] / (MAX_BOXES * 5);                           // 64
    int HW = in_sizes[0] / (nB * (5 + NUM_CLASSES) * NUM_ANCHORS);    // 1444
    int nW = 1; while (nW * nW < HW) ++nW;                            // 38
    int nH = HW / nW;                                                 // 38

    uint32_t* ws   = (uint32_t*)d_ws;
    float*    sumf = (float*)ws;            // ws[0]
    uint32_t* tick = ws + 1;                // ws[1]
    int*      maxb = (int*)(ws + 2);        // ws[2]
    uint32_t* totl = ws + 3;                // ws[3]

    init_ws<<<1, 64, 0, stream>>>(ws);

    int slots = nB * MAX_BOXES;             // 3200
    int rblocks = (slots + 3) / 4;          // 800 blocks, 4 waves each
    fused_all<<<rblocks, 256, 0, stream>>>(output, target, reqd, sumf, maxb,
                                           tick, totl, out, HW, nH, nW, nB);
}